// Round 1
// baseline (433.612 us; speedup 1.0000x reference)
//
#include <hip/hip_runtime.h>

// Input  x: (B=4, C=64, H=512, W=512) fp32
// Output: 4 bands (ll, lh, hl, hh), each (4, 64, 256, 256) fp32,
//         concatenated flat in d_out.
//
// Each thread: 4 output columns of one output row, all 4 bands.
//   reads : 2x float4 from input row 2h, 2x float4 from row 2h+1 (64 B)
//   writes: 1x float4 per band (64 B)

__global__ __launch_bounds__(256) void dwt_haar_kernel(
        const float* __restrict__ x, float* __restrict__ out) {
    const long long tid = (long long)blockIdx.x * blockDim.x + threadIdx.x;
    // total threads = B*C*outH * (outW/4) = 4*64*256 * 64 = 4,194,304
    const int       ow4 = (int)(tid & 63);   // which group of 4 output cols
    const long long row = tid >> 6;          // flattened (b, c, oh)
    const int       oh  = (int)(row & 255);
    const long long bc  = row >> 8;          // flattened (b, c)

    // input row pair base: bc*(512*512) + (2*oh)*512 + ow4*8
    const float* in0 = x + bc * (512LL * 512LL) + (long long)(2 * oh) * 512LL
                         + (long long)ow4 * 8LL;
    const float4 r0a = *(const float4*)(in0);
    const float4 r0b = *(const float4*)(in0 + 4);
    const float4 r1a = *(const float4*)(in0 + 512);
    const float4 r1b = *(const float4*)(in0 + 516);

    // de-interleave: a = even cols row0, b = odd cols row0, c/d from row1
    const float a[4] = {r0a.x, r0a.z, r0b.x, r0b.z};
    const float b[4] = {r0a.y, r0a.w, r0b.y, r0b.w};
    const float c[4] = {r1a.x, r1a.z, r1b.x, r1b.z};
    const float d[4] = {r1a.y, r1a.w, r1b.y, r1b.w};

    float ll[4], lh[4], hl[4], hh[4];
#pragma unroll
    for (int j = 0; j < 4; ++j) {
        const float s0 = a[j] + b[j];   // a+b
        const float s1 = a[j] - b[j];   // a-b
        const float t0 = c[j] + d[j];   // c+d
        const float t1 = c[j] - d[j];   // c-d
        ll[j] = (s0 + t0) * 0.5f;
        lh[j] = (s0 - t0) * 0.5f;
        hl[j] = (s1 + t1) * 0.5f;
        hh[j] = (s1 - t1) * 0.5f;
    }

    const long long band = 4LL * 64LL * 256LL * 256LL;  // 16,777,216
    float* o = out + row * 256LL + (long long)ow4 * 4LL;
    *(float4*)(o)            = *(const float4*)ll;
    *(float4*)(o + band)     = *(const float4*)lh;
    *(float4*)(o + 2 * band) = *(const float4*)hl;
    *(float4*)(o + 3 * band) = *(const float4*)hh;
}

extern "C" void kernel_launch(void* const* d_in, const int* in_sizes, int n_in,
                              void* d_out, int out_size, void* d_ws, size_t ws_size,
                              hipStream_t stream) {
    const float* x   = (const float*)d_in[0];
    float*       out = (float*)d_out;
    // total threads = 4,194,304 ; block 256 -> grid 16384
    const int block = 256;
    const int grid  = 4194304 / block;
    dwt_haar_kernel<<<grid, block, 0, stream>>>(x, out);
}

// Round 3
// 416.774 us; speedup vs baseline: 1.0404x; 1.0404x over previous
//
#include <hip/hip_runtime.h>

// Input  x: (B=4, C=64, H=512, W=512) fp32
// Output: 4 bands (ll, lh, hl, hh), each (4, 64, 256, 256) fp32,
//         concatenated flat in d_out.
//
// Pure streaming kernel (each byte touched once) -> nontemporal loads/stores
// (native ext_vector_type needed: HIP's float4 struct is rejected by the
// builtin). Each thread: 4 output columns of one output row, all 4 bands
// (64 B in, 64 B out).

typedef float v4f __attribute__((ext_vector_type(4)));

__global__ __launch_bounds__(256) void dwt_haar_kernel(
        const float* __restrict__ x, float* __restrict__ out) {
    const long long tid = (long long)blockIdx.x * blockDim.x + threadIdx.x;
    // total threads = B*C*outH * (outW/4) = 4*64*256 * 64 = 4,194,304
    const int       ow4 = (int)(tid & 63);   // which group of 4 output cols
    const long long row = tid >> 6;          // flattened (b, c, oh)
    const int       oh  = (int)(row & 255);
    const long long bc  = row >> 8;          // flattened (b, c)

    const float* in0 = x + bc * (512LL * 512LL) + (long long)(2 * oh) * 512LL
                         + (long long)ow4 * 8LL;

    const v4f r0a = __builtin_nontemporal_load((const v4f*)(in0));
    const v4f r0b = __builtin_nontemporal_load((const v4f*)(in0 + 4));
    const v4f r1a = __builtin_nontemporal_load((const v4f*)(in0 + 512));
    const v4f r1b = __builtin_nontemporal_load((const v4f*)(in0 + 516));

    // de-interleave: a = even cols row0, b = odd cols row0, c/d from row1
    const float a[4] = {r0a.x, r0a.z, r0b.x, r0b.z};
    const float b[4] = {r0a.y, r0a.w, r0b.y, r0b.w};
    const float c[4] = {r1a.x, r1a.z, r1b.x, r1b.z};
    const float d[4] = {r1a.y, r1a.w, r1b.y, r1b.w};

    v4f ll, lh, hl, hh;
#pragma unroll
    for (int j = 0; j < 4; ++j) {
        const float s0 = a[j] + b[j];
        const float s1 = a[j] - b[j];
        const float t0 = c[j] + d[j];
        const float t1 = c[j] - d[j];
        ll[j] = (s0 + t0) * 0.5f;
        lh[j] = (s0 - t0) * 0.5f;
        hl[j] = (s1 + t1) * 0.5f;
        hh[j] = (s1 - t1) * 0.5f;
    }

    const long long band = 4LL * 64LL * 256LL * 256LL;  // 16,777,216
    float* o = out + row * 256LL + (long long)ow4 * 4LL;
    __builtin_nontemporal_store(ll, (v4f*)(o));
    __builtin_nontemporal_store(lh, (v4f*)(o + band));
    __builtin_nontemporal_store(hl, (v4f*)(o + 2 * band));
    __builtin_nontemporal_store(hh, (v4f*)(o + 3 * band));
}

extern "C" void kernel_launch(void* const* d_in, const int* in_sizes, int n_in,
                              void* d_out, int out_size, void* d_ws, size_t ws_size,
                              hipStream_t stream) {
    const float* x   = (const float*)d_in[0];
    float*       out = (float*)d_out;
    const int block = 256;
    const int grid  = 4194304 / block;  // 16384
    dwt_haar_kernel<<<grid, block, 0, stream>>>(x, out);
}